// Round 3
// baseline (448.297 us; speedup 1.0000x reference)
//
#include <hip/hip_runtime.h>
#include <hip/hip_cooperative_groups.h>

namespace cg = cooperative_groups;

// TT-matrix embedding: vocab 50*60*60, embed 8*8*8, rank 16.
//
// Round-3 scheme: counting-sort by pair=(i1,i2) fused into ONE cooperative kernel
// (zero -> hist -> LDS scan -> scatter with grid.sync between phases), then one
// block per pair-group for the embed (t12 computed in registers from c1/c2,
// identical FMA order across rounds -> identical absmax). Output stored with
// nontemporal hints (write-once stream, keep L2 for rec/c2/c3).
//
// Round-2 post-mortem: structural wins moved total only ~4-6 us/round =>
// timed region carries ~240-250 us of harness-fixed poison/memset work
// (1 GiB ws fill ~162 us visible in top-5 every round). Our controllable
// portion is ~75-85 us with a 268 MB out-write floor of ~43 us. This round
// attacks the remaining ~25 us: 5 launches -> 2, global-mem Hillis-Steele
// scan -> 256-thread LDS scan, NT stores.

#define M2M3  3600u
#define M3    60u
#define NPAIR 3000
#define NPAIR_PAD 3072

typedef float vf4 __attribute__((ext_vector_type(4)));

// ---------------- Fused cooperative sort: zero | hist | scan | scatter ----------------
// 256 blocks x 256 threads = 1 block/CU (co-residency guaranteed), grid-stride phases.
__global__ __launch_bounds__(256) void tt_sort_coop(
    const int* __restrict__ x,
    unsigned* __restrict__ counts,
    unsigned* __restrict__ cursor,
    unsigned* __restrict__ rec,
    int T)
{
    cg::grid_group grid = cg::this_grid();
    const int tid = blockIdx.x * blockDim.x + threadIdx.x;
    const int nth = gridDim.x * blockDim.x;

    // phase 0: zero histogram
    for (int i = tid; i < NPAIR_PAD; i += nth) counts[i] = 0u;
    grid.sync();

    // phase 1: histogram over pairs
    for (int t = tid; t < T; t += nth)
        atomicAdd(&counts[(unsigned)x[t] / M3], 1u);
    grid.sync();

    // phase 2: exclusive scan of 3000 counts -> cursor (block 0, LDS two-level)
    if (blockIdx.x == 0) {
        __shared__ unsigned part[256];
        const int base = threadIdx.x * 12;           // 256*12 = 3072 >= NPAIR
        unsigned v[12];
        unsigned s = 0;
#pragma unroll
        for (int k = 0; k < 12; ++k) {
            const unsigned c = (base + k < NPAIR) ? counts[base + k] : 0u;
            v[k] = s;                                // exclusive within chunk
            s += c;
        }
        part[threadIdx.x] = s;
        __syncthreads();
        unsigned inc = s;
        for (int off = 1; off < 256; off <<= 1) {    // Hillis-Steele over 256 partials
            const unsigned add = (threadIdx.x >= off) ? part[threadIdx.x - off] : 0u;
            __syncthreads();
            inc += add;
            part[threadIdx.x] = inc;
            __syncthreads();
        }
        const unsigned chunk_excl = inc - s;
#pragma unroll
        for (int k = 0; k < 12; ++k)
            if (base + k < NPAIR) cursor[base + k] = chunk_excl + v[k];
    }
    grid.sync();

    // phase 3: scatter records; after this, cursor[p] = group END
    for (int t = tid; t < T; t += nth) {
        const unsigned id   = (unsigned)x[t];
        const unsigned pair = id / M3;
        const unsigned i3   = id - pair * M3;
        const unsigned pos  = atomicAdd(&cursor[pair], 1u);
        rec[pos] = ((unsigned)t << 6) | i3;          // t:17b | i3:6b
    }
}

// ---------------- Per-pair-group embed ----------------
// grid = NPAIR blocks x 256 threads (4 waves). start = cursor[p] - counts[p].
// Each wave computes the pair's t12 row in registers, then serially processes its
// quarter of the group's tokens via readlane-broadcast records.
__global__ __launch_bounds__(256) void tt_embed_grouped(
    const unsigned* __restrict__ rec,
    const unsigned* __restrict__ counts,
    const unsigned* __restrict__ cursor,
    const float* __restrict__ c1,   // [50][8][16]
    const float* __restrict__ c2,   // [60][16][8][16]
    const float* __restrict__ c3,   // [60][16][8]
    float* __restrict__ out)        // [T][512]
{
    const int p    = blockIdx.x;            // pair = i1*60 + i2
    const int lane = threadIdx.x & 63;
    const int w    = threadIdx.x >> 6;      // wave 0..3
    const int a    = lane >> 3;
    const int b    = lane & 7;

    unsigned end = cursor[p];
    unsigned cnt = counts[p];
    end = __builtin_amdgcn_readfirstlane(end);
    cnt = __builtin_amdgcn_readfirstlane(cnt);
    const unsigned start = end - cnt;

    const unsigned q = cnt >> 2, r = cnt & 3u;
    const unsigned nw = q + ((unsigned)w < r ? 1u : 0u);
    if (nw == 0) return;                    // no barriers below -> safe wave exit
    const unsigned bw = start + (unsigned)w * q + min((unsigned)w, r);

    // ---- t12 row for this pair, in registers (same FMA order as prior rounds) ----
    const int i1 = p / 60;
    const int i2 = p - i1 * 60;
    const float4* __restrict__ g1v = (const float4*)(c1 + i1 * 128 + a * 16);
    const float*  __restrict__ g2  = c2 + i2 * 2048 + b * 16;

    float4 a1q[4];
#pragma unroll
    for (int k = 0; k < 4; ++k) a1q[k] = g1v[k];
    const float* a1f = (const float*)a1q;

    float4 t4[4];
#pragma unroll
    for (int k = 0; k < 4; ++k) t4[k] = make_float4(0.f, 0.f, 0.f, 0.f);
#pragma unroll
    for (int rr = 0; rr < 16; ++rr) {
        const float a1 = a1f[rr];
        const float4* row = (const float4*)(g2 + rr * 128);
#pragma unroll
        for (int k = 0; k < 4; ++k) {
            const float4 v = row[k];
            t4[k].x = fmaf(a1, v.x, t4[k].x);
            t4[k].y = fmaf(a1, v.y, t4[k].y);
            t4[k].z = fmaf(a1, v.z, t4[k].z);
            t4[k].w = fmaf(a1, v.w, t4[k].w);
        }
    }
    const float* tf = (const float*)t4;     // tf[s], s = 0..15

    // ---- token loop over this wave's share (batches of 64 records) ----
    for (unsigned off = 0; off < nw; off += 64u) {
        const unsigned m = min(64u, nw - off);      // wave-uniform
        unsigned rj = 0u;
        if ((unsigned)lane < m) rj = rec[bw + off + (unsigned)lane];

        for (unsigned j = 0; j < m; ++j) {
            const unsigned rv = __builtin_amdgcn_readlane(rj, (int)j);
            const unsigned t  = rv >> 6;
            const unsigned i3 = rv & 63u;

            const float4* __restrict__ g3 = (const float4*)(c3 + i3 * 128u);

            float o[8];
#pragma unroll
            for (int c = 0; c < 8; ++c) o[c] = 0.f;
#pragma unroll
            for (int s = 0; s < 16; ++s) {
                const float ts = tf[s];
                const float4 w0 = g3[s * 2 + 0];
                const float4 w1 = g3[s * 2 + 1];
                o[0] = fmaf(ts, w0.x, o[0]);
                o[1] = fmaf(ts, w0.y, o[1]);
                o[2] = fmaf(ts, w0.z, o[2]);
                o[3] = fmaf(ts, w0.w, o[3]);
                o[4] = fmaf(ts, w1.x, o[4]);
                o[5] = fmaf(ts, w1.y, o[5]);
                o[6] = fmaf(ts, w1.z, o[6]);
                o[7] = fmaf(ts, w1.w, o[7]);
            }

            // nontemporal: out is a write-once stream, never re-read
            vf4* dst = (vf4*)(out + (size_t)t * 512u + lane * 8);
            const vf4 r0 = {o[0], o[1], o[2], o[3]};
            const vf4 r1 = {o[4], o[5], o[6], o[7]};
            __builtin_nontemporal_store(r0, dst);
            __builtin_nontemporal_store(r1, dst + 1);
        }
    }
}

// ---------------- Fallback sort chain (if cooperative launch unavailable) ----------------
__global__ __launch_bounds__(256) void tt_zero(unsigned* __restrict__ counts)
{
    const int i = blockIdx.x * blockDim.x + threadIdx.x;
    if (i < NPAIR_PAD) counts[i] = 0u;
}

__global__ __launch_bounds__(256) void tt_hist(
    const int* __restrict__ x, unsigned* __restrict__ counts, int T)
{
    const int t = blockIdx.x * blockDim.x + threadIdx.x;
    if (t >= T) return;
    atomicAdd(&counts[(unsigned)x[t] / M3], 1u);
}

__global__ __launch_bounds__(1024) void tt_scan(
    const unsigned* __restrict__ counts, unsigned* __restrict__ cursor)
{
    __shared__ unsigned buf[1024];
    const int tid = threadIdx.x;
    const int b = tid * 3;
    unsigned c0 = 0, c1 = 0, c2 = 0;
    if (b     < NPAIR) c0 = counts[b];
    if (b + 1 < NPAIR) c1 = counts[b + 1];
    if (b + 2 < NPAIR) c2 = counts[b + 2];
    const unsigned local = c0 + c1 + c2;
    buf[tid] = local;
    __syncthreads();
    for (int off = 1; off < 1024; off <<= 1) {
        const unsigned v = (tid >= off) ? buf[tid - off] : 0u;
        __syncthreads();
        buf[tid] += v;
        __syncthreads();
    }
    const unsigned excl = buf[tid] - local;
    if (b     < NPAIR) cursor[b]     = excl;
    if (b + 1 < NPAIR) cursor[b + 1] = excl + c0;
    if (b + 2 < NPAIR) cursor[b + 2] = excl + c0 + c1;
}

__global__ __launch_bounds__(256) void tt_scatter(
    const int* __restrict__ x, unsigned* __restrict__ cursor,
    unsigned* __restrict__ rec, int T)
{
    const int t = blockIdx.x * blockDim.x + threadIdx.x;
    if (t >= T) return;
    const unsigned id   = (unsigned)x[t];
    const unsigned pair = id / M3;
    const unsigned i3   = id - pair * M3;
    const unsigned pos  = atomicAdd(&cursor[pair], 1u);
    rec[pos] = ((unsigned)t << 6) | i3;
}

// ---------------- Fallback A: two-phase via tab (needs 12.3 MB ws) ----------------
__global__ __launch_bounds__(256) void tt_pair_kernel(
    const float* __restrict__ c1, const float* __restrict__ c2,
    float* __restrict__ tab)
{
    const int pair = blockIdx.x;
    const int i1 = pair / 60;
    const int i2 = pair - i1 * 60;
    const int tid = threadIdx.x;
    const int qq = tid >> 6;
    const int ab = tid & 63;
    const int a  = ab >> 3;
    const int b  = ab & 7;
    const float* __restrict__ g1 = c1 + i1 * 128 + a * 16;
    const float* __restrict__ g2 = c2 + i2 * 2048 + b * 16 + qq * 4;
    float4 acc = make_float4(0.f, 0.f, 0.f, 0.f);
#pragma unroll
    for (int rr = 0; rr < 16; ++rr) {
        const float a1 = g1[rr];
        const float4 v = *(const float4*)(g2 + rr * 128);
        acc.x = fmaf(a1, v.x, acc.x);
        acc.y = fmaf(a1, v.y, acc.y);
        acc.z = fmaf(a1, v.z, acc.z);
        acc.w = fmaf(a1, v.w, acc.w);
    }
    *(float4*)(tab + (size_t)pair * 1024 + tid * 4) = acc;
}

__global__ __launch_bounds__(256) void tt_embed2_kernel(
    const int* __restrict__ x, const float* __restrict__ c3,
    const float* __restrict__ tab, float* __restrict__ out, int T)
{
    const int u    = (int)((blockIdx.x * blockDim.x + threadIdx.x) >> 6);
    const int lane = threadIdx.x & 63;
    if (u >= T) return;
    const unsigned id  = __builtin_amdgcn_readfirstlane((unsigned)x[u]);
    const unsigned i1  = id / M2M3;
    const unsigned rem = id - i1 * M2M3;
    const unsigned i2  = rem / M3;
    const unsigned i3  = rem - i2 * M3;
    const float* tp = tab + (size_t)(i1 * 60u + i2) * 1024u;
    float4 t[4];
#pragma unroll
    for (int k = 0; k < 4; ++k)
        t[k] = *(const float4*)(tp + k * 256 + lane * 4);
    const float* tf = (const float*)t;
    const float4* __restrict__ g3 = (const float4*)(c3 + i3 * 128u);
    float o[8];
#pragma unroll
    for (int c = 0; c < 8; ++c) o[c] = 0.f;
#pragma unroll
    for (int s = 0; s < 16; ++s) {
        const float ts = tf[s];
        const float4 w0 = g3[s * 2 + 0];
        const float4 w1 = g3[s * 2 + 1];
        o[0]=fmaf(ts,w0.x,o[0]); o[1]=fmaf(ts,w0.y,o[1]);
        o[2]=fmaf(ts,w0.z,o[2]); o[3]=fmaf(ts,w0.w,o[3]);
        o[4]=fmaf(ts,w1.x,o[4]); o[5]=fmaf(ts,w1.y,o[5]);
        o[6]=fmaf(ts,w1.z,o[6]); o[7]=fmaf(ts,w1.w,o[7]);
    }
    float4* dst = (float4*)(out + (size_t)u * 512 + lane * 8);
    dst[0] = make_float4(o[0], o[1], o[2], o[3]);
    dst[1] = make_float4(o[4], o[5], o[6], o[7]);
}

// ---------------- Fallback B: single-pass (tiny ws) ----------------
__global__ __launch_bounds__(256) void tt_embed_kernel(
    const int* __restrict__ x, const float* __restrict__ c1,
    const float* __restrict__ c2, const float* __restrict__ c3,
    float* __restrict__ out, int T)
{
    const int u    = (int)((blockIdx.x * blockDim.x + threadIdx.x) >> 6);
    const int lane = threadIdx.x & 63;
    if (u >= T) return;
    const int a = lane >> 3, b = lane & 7;
    const unsigned id  = (unsigned)x[u];
    const unsigned i1  = id / M2M3;
    const unsigned rem = id - i1 * M2M3;
    const unsigned i2  = rem / M3;
    const unsigned i3  = rem - i2 * M3;
    const float4* g1 = (const float4*)(c1 + i1 * 128u + a * 16);
    const float*  g2 = c2 + i2 * 2048u + b * 16;
    const float4* g3 = (const float4*)(c3 + i3 * 128u);
    float4 a1v[4];
#pragma unroll
    for (int k = 0; k < 4; ++k) a1v[k] = g1[k];
    const float* a1f = (const float*)a1v;
    float t12[16];
#pragma unroll
    for (int s = 0; s < 16; ++s) t12[s] = 0.f;
#pragma unroll
    for (int rr = 0; rr < 16; ++rr) {
        const float a1 = a1f[rr];
        const float4* row = (const float4*)(g2 + rr * 128);
#pragma unroll
        for (int k = 0; k < 4; ++k) {
            const float4 v = row[k];
            t12[k*4+0] = fmaf(a1, v.x, t12[k*4+0]);
            t12[k*4+1] = fmaf(a1, v.y, t12[k*4+1]);
            t12[k*4+2] = fmaf(a1, v.z, t12[k*4+2]);
            t12[k*4+3] = fmaf(a1, v.w, t12[k*4+3]);
        }
    }
    float o[8];
#pragma unroll
    for (int c = 0; c < 8; ++c) o[c] = 0.f;
#pragma unroll
    for (int s = 0; s < 16; ++s) {
        const float ts = t12[s];
        const float4 w0 = g3[s*2+0];
        const float4 w1 = g3[s*2+1];
        o[0]=fmaf(ts,w0.x,o[0]); o[1]=fmaf(ts,w0.y,o[1]);
        o[2]=fmaf(ts,w0.z,o[2]); o[3]=fmaf(ts,w0.w,o[3]);
        o[4]=fmaf(ts,w1.x,o[4]); o[5]=fmaf(ts,w1.y,o[5]);
        o[6]=fmaf(ts,w1.z,o[6]); o[7]=fmaf(ts,w1.w,o[7]);
    }
    float4* dst = (float4*)(out + (size_t)u * 512 + lane * 8);
    dst[0] = make_float4(o[0], o[1], o[2], o[3]);
    dst[1] = make_float4(o[4], o[5], o[6], o[7]);
}

extern "C" void kernel_launch(void* const* d_in, const int* in_sizes, int n_in,
                              void* d_out, int out_size, void* d_ws, size_t ws_size,
                              hipStream_t stream) {
    const int*   x  = (const int*)d_in[0];
    const float* c1 = (const float*)d_in[1];
    const float* c2 = (const float*)d_in[2];
    const float* c3 = (const float*)d_in[3];
    float* out = (float*)d_out;

    const int T = in_sizes[0];                        // 131072 tokens

    // sorted-path workspace: counts[3072] | cursor[3072] | rec[T]  (~550 KB)
    const size_t off_counts = 0;
    const size_t off_cursor = off_counts + (size_t)NPAIR_PAD * 4u;
    const size_t off_rec    = off_cursor + (size_t)NPAIR_PAD * 4u;
    const size_t need_sort  = off_rec + (size_t)T * 4u;
    const size_t tab_bytes  = (size_t)NPAIR * 1024u * sizeof(float);

    char* ws = (char*)d_ws;

    if (ws_size >= need_sort) {
        unsigned* counts = (unsigned*)(ws + off_counts);
        unsigned* cursor = (unsigned*)(ws + off_cursor);
        unsigned* rec    = (unsigned*)(ws + off_rec);

        void* args[] = { (void*)&x, (void*)&counts, (void*)&cursor,
                         (void*)&rec, (void*)&T };
        const hipError_t ce = hipLaunchCooperativeKernel(
            (const void*)tt_sort_coop, dim3(256), dim3(256), args, 0, stream);
        if (ce != hipSuccess) {
            // fallback: separate sort chain
            tt_zero<<<(NPAIR_PAD + 255) / 256, 256, 0, stream>>>(counts);
            tt_hist<<<(T + 255) / 256, 256, 0, stream>>>(x, counts, T);
            tt_scan<<<1, 1024, 0, stream>>>(counts, cursor);
            tt_scatter<<<(T + 255) / 256, 256, 0, stream>>>(x, cursor, rec, T);
        }
        tt_embed_grouped<<<NPAIR, 256, 0, stream>>>(rec, counts, cursor,
                                                    c1, c2, c3, out);
    } else if (ws_size >= tab_bytes) {
        float* tab = (float*)ws;
        tt_pair_kernel<<<NPAIR, 256, 0, stream>>>(c1, c2, tab);
        const int blocks = (T + 3) / 4;
        tt_embed2_kernel<<<blocks, 256, 0, stream>>>(x, c3, tab, out, T);
    } else {
        const int blocks = (T + 3) / 4;
        tt_embed_kernel<<<blocks, 256, 0, stream>>>(x, c1, c2, c3, out, T);
    }
}

// Round 4
// 339.221 us; speedup vs baseline: 1.3215x; 1.3215x over previous
//
#include <hip/hip_runtime.h>

// TT-matrix embedding: vocab 50*60*60, embed 8*8*8, rank 16.
//
// Round-4 scheme: bucketed counting sort (NO hist, NO scan, NO cooperative launch):
//   - rec has a fixed 128-slot bucket per pair (3000*128*4 = 1.5 MB in d_ws).
//     Group sizes are multinomial(131072, 1/3000): mean 43.7, sigma 6.6; 128 is
//     mean+12.8 sigma -- deterministic input cannot overflow (guarded: T<=200000,
//     else fall back to the full hist+scan chain).
//   - 3 launches: iota(cursor[p]=p*128) -> scatter(atomic append) -> embed.
//   - embed: one block (4 waves) per pair; each wave computes the pair's t12 row
//     in registers from c1/c2 (identical FMA order since round 0 -> identical
//     absmax) and serially processes its quarter of the bucket via readlane.
//
// Round-3 post-mortem: cooperative grid.sync (3x, 256 blocks) + 1-block/CU
// occupancy cost ~124 us -- an order of magnitude worse than the 4 launches it
// replaced. Reverted; NT stores reverted too (confounded in the same bundle).
// Fixed harness work in the timed region is ~250 us (1 GiB ws poison ~162 us in
// top-5 every round); our controllable portion ~75 us, floor ~48 us.

#define M2M3  3600u
#define M3    60u
#define NPAIR 3000
#define NPAIR_PAD 3072
#define CAP   128           // bucket slots per pair

// ---------------- bucketed path: iota -> scatter -> embed ----------------
__global__ __launch_bounds__(256) void tt_iota(unsigned* __restrict__ cursor)
{
    const int i = blockIdx.x * blockDim.x + threadIdx.x;
    if (i < NPAIR_PAD) cursor[i] = (unsigned)i * CAP;
}

__global__ __launch_bounds__(256) void tt_scatter_bucket(
    const int* __restrict__ x, unsigned* __restrict__ cursor,
    unsigned* __restrict__ rec, int T)
{
    const int t = blockIdx.x * blockDim.x + threadIdx.x;
    if (t >= T) return;
    const unsigned id   = (unsigned)x[t];
    const unsigned pair = id / M3;
    const unsigned i3   = id - pair * M3;
    const unsigned pos  = atomicAdd(&cursor[pair], 1u);
    if (pos < (pair + 1u) * CAP)            // impossible overflow guard
        rec[pos] = ((unsigned)t << 6) | i3; // t:17b | i3:6b
}

// grid = NPAIR blocks x 256 threads (4 waves). start = p*CAP, cnt = cursor[p]-start.
__global__ __launch_bounds__(256) void tt_embed_bucket(
    const unsigned* __restrict__ rec,
    const unsigned* __restrict__ cursor,
    const float* __restrict__ c1,   // [50][8][16]
    const float* __restrict__ c2,   // [60][16][8][16]
    const float* __restrict__ c3,   // [60][16][8]
    float* __restrict__ out)        // [T][512]
{
    const int p    = blockIdx.x;            // pair = i1*60 + i2
    const int lane = threadIdx.x & 63;
    const int w    = threadIdx.x >> 6;      // wave 0..3
    const int a    = lane >> 3;
    const int b    = lane & 7;

    const unsigned start = (unsigned)p * CAP;
    unsigned end = cursor[p];
    end = __builtin_amdgcn_readfirstlane(end);
    unsigned cnt = end - start;
    if (cnt > CAP) cnt = CAP;               // paranoia vs overflow guard

    const unsigned q = cnt >> 2, r = cnt & 3u;
    const unsigned nw = q + ((unsigned)w < r ? 1u : 0u);
    if (nw == 0) return;                    // no barriers below -> safe wave exit
    const unsigned bw = start + (unsigned)w * q + min((unsigned)w, r);

    // ---- t12 row for this pair, in registers (same FMA order as prior rounds) ----
    const int i1 = p / 60;
    const int i2 = p - i1 * 60;
    const float4* __restrict__ g1v = (const float4*)(c1 + i1 * 128 + a * 16);
    const float*  __restrict__ g2  = c2 + i2 * 2048 + b * 16;

    float4 a1q[4];
#pragma unroll
    for (int k = 0; k < 4; ++k) a1q[k] = g1v[k];
    const float* a1f = (const float*)a1q;

    float4 t4[4];
#pragma unroll
    for (int k = 0; k < 4; ++k) t4[k] = make_float4(0.f, 0.f, 0.f, 0.f);
#pragma unroll
    for (int rr = 0; rr < 16; ++rr) {
        const float a1 = a1f[rr];
        const float4* row = (const float4*)(g2 + rr * 128);
#pragma unroll
        for (int k = 0; k < 4; ++k) {
            const float4 v = row[k];
            t4[k].x = fmaf(a1, v.x, t4[k].x);
            t4[k].y = fmaf(a1, v.y, t4[k].y);
            t4[k].z = fmaf(a1, v.z, t4[k].z);
            t4[k].w = fmaf(a1, v.w, t4[k].w);
        }
    }
    const float* tf = (const float*)t4;     // tf[s], s = 0..15

    // ---- token loop over this wave's share (batches of 64 records) ----
    for (unsigned off = 0; off < nw; off += 64u) {
        const unsigned m = min(64u, nw - off);      // wave-uniform
        unsigned rj = 0u;
        if ((unsigned)lane < m) rj = rec[bw + off + (unsigned)lane];

        for (unsigned j = 0; j < m; ++j) {
            const unsigned rv = __builtin_amdgcn_readlane(rj, (int)j);
            const unsigned t  = rv >> 6;
            const unsigned i3 = rv & 63u;

            const float4* __restrict__ g3 = (const float4*)(c3 + i3 * 128u);

            float o[8];
#pragma unroll
            for (int c = 0; c < 8; ++c) o[c] = 0.f;
#pragma unroll
            for (int s = 0; s < 16; ++s) {
                const float ts = tf[s];
                const float4 w0 = g3[s * 2 + 0];
                const float4 w1 = g3[s * 2 + 1];
                o[0] = fmaf(ts, w0.x, o[0]);
                o[1] = fmaf(ts, w0.y, o[1]);
                o[2] = fmaf(ts, w0.z, o[2]);
                o[3] = fmaf(ts, w0.w, o[3]);
                o[4] = fmaf(ts, w1.x, o[4]);
                o[5] = fmaf(ts, w1.y, o[5]);
                o[6] = fmaf(ts, w1.z, o[6]);
                o[7] = fmaf(ts, w1.w, o[7]);
            }

            float4* dst = (float4*)(out + (size_t)t * 512u + lane * 8);
            dst[0] = make_float4(o[0], o[1], o[2], o[3]);
            dst[1] = make_float4(o[4], o[5], o[6], o[7]);
        }
    }
}

// ---------------- fallback sort chain (large T): zero|hist|scan|scatter ----------------
__global__ __launch_bounds__(256) void tt_zero(unsigned* __restrict__ counts)
{
    const int i = blockIdx.x * blockDim.x + threadIdx.x;
    if (i < NPAIR_PAD) counts[i] = 0u;
}

__global__ __launch_bounds__(256) void tt_hist(
    const int* __restrict__ x, unsigned* __restrict__ counts, int T)
{
    const int t = blockIdx.x * blockDim.x + threadIdx.x;
    if (t >= T) return;
    atomicAdd(&counts[(unsigned)x[t] / M3], 1u);
}

__global__ __launch_bounds__(1024) void tt_scan(
    const unsigned* __restrict__ counts, unsigned* __restrict__ cursor)
{
    __shared__ unsigned buf[1024];
    const int tid = threadIdx.x;
    const int b = tid * 3;
    unsigned c0 = 0, c1 = 0, c2 = 0;
    if (b     < NPAIR) c0 = counts[b];
    if (b + 1 < NPAIR) c1 = counts[b + 1];
    if (b + 2 < NPAIR) c2 = counts[b + 2];
    const unsigned local = c0 + c1 + c2;
    buf[tid] = local;
    __syncthreads();
    for (int off = 1; off < 1024; off <<= 1) {
        const unsigned v = (tid >= off) ? buf[tid - off] : 0u;
        __syncthreads();
        buf[tid] += v;
        __syncthreads();
    }
    const unsigned excl = buf[tid] - local;
    if (b     < NPAIR) cursor[b]     = excl;
    if (b + 1 < NPAIR) cursor[b + 1] = excl + c0;
    if (b + 2 < NPAIR) cursor[b + 2] = excl + c0 + c1;
}

__global__ __launch_bounds__(256) void tt_scatter(
    const int* __restrict__ x, unsigned* __restrict__ cursor,
    unsigned* __restrict__ rec, int T)
{
    const int t = blockIdx.x * blockDim.x + threadIdx.x;
    if (t >= T) return;
    const unsigned id   = (unsigned)x[t];
    const unsigned pair = id / M3;
    const unsigned i3   = id - pair * M3;
    const unsigned pos  = atomicAdd(&cursor[pair], 1u);
    rec[pos] = ((unsigned)t << 6) | i3;
}

// embed for the contiguous (scanned) layout: start = cursor[p]-counts[p]
__global__ __launch_bounds__(256) void tt_embed_grouped(
    const unsigned* __restrict__ rec,
    const unsigned* __restrict__ counts,
    const unsigned* __restrict__ cursor,
    const float* __restrict__ c1, const float* __restrict__ c2,
    const float* __restrict__ c3, float* __restrict__ out)
{
    const int p    = blockIdx.x;
    const int lane = threadIdx.x & 63;
    const int w    = threadIdx.x >> 6;
    const int a    = lane >> 3;
    const int b    = lane & 7;

    unsigned end = cursor[p];
    unsigned cnt = counts[p];
    end = __builtin_amdgcn_readfirstlane(end);
    cnt = __builtin_amdgcn_readfirstlane(cnt);
    const unsigned start = end - cnt;

    const unsigned q = cnt >> 2, r = cnt & 3u;
    const unsigned nw = q + ((unsigned)w < r ? 1u : 0u);
    if (nw == 0) return;
    const unsigned bw = start + (unsigned)w * q + min((unsigned)w, r);

    const int i1 = p / 60;
    const int i2 = p - i1 * 60;
    const float4* __restrict__ g1v = (const float4*)(c1 + i1 * 128 + a * 16);
    const float*  __restrict__ g2  = c2 + i2 * 2048 + b * 16;

    float4 a1q[4];
#pragma unroll
    for (int k = 0; k < 4; ++k) a1q[k] = g1v[k];
    const float* a1f = (const float*)a1q;

    float4 t4[4];
#pragma unroll
    for (int k = 0; k < 4; ++k) t4[k] = make_float4(0.f, 0.f, 0.f, 0.f);
#pragma unroll
    for (int rr = 0; rr < 16; ++rr) {
        const float a1 = a1f[rr];
        const float4* row = (const float4*)(g2 + rr * 128);
#pragma unroll
        for (int k = 0; k < 4; ++k) {
            const float4 v = row[k];
            t4[k].x = fmaf(a1, v.x, t4[k].x);
            t4[k].y = fmaf(a1, v.y, t4[k].y);
            t4[k].z = fmaf(a1, v.z, t4[k].z);
            t4[k].w = fmaf(a1, v.w, t4[k].w);
        }
    }
    const float* tf = (const float*)t4;

    for (unsigned off = 0; off < nw; off += 64u) {
        const unsigned m = min(64u, nw - off);
        unsigned rj = 0u;
        if ((unsigned)lane < m) rj = rec[bw + off + (unsigned)lane];

        for (unsigned j = 0; j < m; ++j) {
            const unsigned rv = __builtin_amdgcn_readlane(rj, (int)j);
            const unsigned t  = rv >> 6;
            const unsigned i3 = rv & 63u;
            const float4* __restrict__ g3 = (const float4*)(c3 + i3 * 128u);

            float o[8];
#pragma unroll
            for (int c = 0; c < 8; ++c) o[c] = 0.f;
#pragma unroll
            for (int s = 0; s < 16; ++s) {
                const float ts = tf[s];
                const float4 w0 = g3[s * 2 + 0];
                const float4 w1 = g3[s * 2 + 1];
                o[0]=fmaf(ts,w0.x,o[0]); o[1]=fmaf(ts,w0.y,o[1]);
                o[2]=fmaf(ts,w0.z,o[2]); o[3]=fmaf(ts,w0.w,o[3]);
                o[4]=fmaf(ts,w1.x,o[4]); o[5]=fmaf(ts,w1.y,o[5]);
                o[6]=fmaf(ts,w1.z,o[6]); o[7]=fmaf(ts,w1.w,o[7]);
            }
            float4* dst = (float4*)(out + (size_t)t * 512u + lane * 8);
            dst[0] = make_float4(o[0], o[1], o[2], o[3]);
            dst[1] = make_float4(o[4], o[5], o[6], o[7]);
        }
    }
}

// ---------------- Fallback B: single-pass (tiny ws) ----------------
__global__ __launch_bounds__(256) void tt_embed_kernel(
    const int* __restrict__ x, const float* __restrict__ c1,
    const float* __restrict__ c2, const float* __restrict__ c3,
    float* __restrict__ out, int T)
{
    const int u    = (int)((blockIdx.x * blockDim.x + threadIdx.x) >> 6);
    const int lane = threadIdx.x & 63;
    if (u >= T) return;
    const int a = lane >> 3, b = lane & 7;
    const unsigned id  = (unsigned)x[u];
    const unsigned i1  = id / M2M3;
    const unsigned rem = id - i1 * M2M3;
    const unsigned i2  = rem / M3;
    const unsigned i3  = rem - i2 * M3;
    const float4* g1 = (const float4*)(c1 + i1 * 128u + a * 16);
    const float*  g2 = c2 + i2 * 2048u + b * 16;
    const float4* g3 = (const float4*)(c3 + i3 * 128u);
    float4 a1v[4];
#pragma unroll
    for (int k = 0; k < 4; ++k) a1v[k] = g1[k];
    const float* a1f = (const float*)a1v;
    float t12[16];
#pragma unroll
    for (int s = 0; s < 16; ++s) t12[s] = 0.f;
#pragma unroll
    for (int rr = 0; rr < 16; ++rr) {
        const float a1 = a1f[rr];
        const float4* row = (const float4*)(g2 + rr * 128);
#pragma unroll
        for (int k = 0; k < 4; ++k) {
            const float4 v = row[k];
            t12[k*4+0] = fmaf(a1, v.x, t12[k*4+0]);
            t12[k*4+1] = fmaf(a1, v.y, t12[k*4+1]);
            t12[k*4+2] = fmaf(a1, v.z, t12[k*4+2]);
            t12[k*4+3] = fmaf(a1, v.w, t12[k*4+3]);
        }
    }
    float o[8];
#pragma unroll
    for (int c = 0; c < 8; ++c) o[c] = 0.f;
#pragma unroll
    for (int s = 0; s < 16; ++s) {
        const float ts = t12[s];
        const float4 w0 = g3[s*2+0];
        const float4 w1 = g3[s*2+1];
        o[0]=fmaf(ts,w0.x,o[0]); o[1]=fmaf(ts,w0.y,o[1]);
        o[2]=fmaf(ts,w0.z,o[2]); o[3]=fmaf(ts,w0.w,o[3]);
        o[4]=fmaf(ts,w1.x,o[4]); o[5]=fmaf(ts,w1.y,o[5]);
        o[6]=fmaf(ts,w1.z,o[6]); o[7]=fmaf(ts,w1.w,o[7]);
    }
    float4* dst = (float4*)(out + (size_t)u * 512 + lane * 8);
    dst[0] = make_float4(o[0], o[1], o[2], o[3]);
    dst[1] = make_float4(o[4], o[5], o[6], o[7]);
}

extern "C" void kernel_launch(void* const* d_in, const int* in_sizes, int n_in,
                              void* d_out, int out_size, void* d_ws, size_t ws_size,
                              hipStream_t stream) {
    const int*   x  = (const int*)d_in[0];
    const float* c1 = (const float*)d_in[1];
    const float* c2 = (const float*)d_in[2];
    const float* c3 = (const float*)d_in[3];
    float* out = (float*)d_out;

    const int T = in_sizes[0];                        // 131072 tokens

    // bucketed layout: cursor[3072] | rec[NPAIR*CAP]  (~1.55 MB)
    const size_t bk_off_cursor = 0;
    const size_t bk_off_rec    = (size_t)NPAIR_PAD * 4u;
    const size_t bk_need       = bk_off_rec + (size_t)NPAIR * CAP * 4u;

    // contiguous layout (fallback for large T): counts|cursor|rec[T]
    const size_t ct_off_counts = 0;
    const size_t ct_off_cursor = ct_off_counts + (size_t)NPAIR_PAD * 4u;
    const size_t ct_off_rec    = ct_off_cursor + (size_t)NPAIR_PAD * 4u;
    const size_t ct_need       = ct_off_rec + (size_t)T * 4u;

    char* ws = (char*)d_ws;

    if (T <= 200000 && ws_size >= bk_need) {
        // bucketed path: 3 launches, no hist, no scan
        unsigned* cursor = (unsigned*)(ws + bk_off_cursor);
        unsigned* rec    = (unsigned*)(ws + bk_off_rec);

        tt_iota<<<(NPAIR_PAD + 255) / 256, 256, 0, stream>>>(cursor);
        tt_scatter_bucket<<<(T + 255) / 256, 256, 0, stream>>>(x, cursor, rec, T);
        tt_embed_bucket<<<NPAIR, 256, 0, stream>>>(rec, cursor, c1, c2, c3, out);
    } else if (ws_size >= ct_need) {
        // contiguous sort chain (round-2 proven path)
        unsigned* counts = (unsigned*)(ws + ct_off_counts);
        unsigned* cursor = (unsigned*)(ws + ct_off_cursor);
        unsigned* rec    = (unsigned*)(ws + ct_off_rec);

        tt_zero<<<(NPAIR_PAD + 255) / 256, 256, 0, stream>>>(counts);
        tt_hist<<<(T + 255) / 256, 256, 0, stream>>>(x, counts, T);
        tt_scan<<<1, 1024, 0, stream>>>(counts, cursor);
        tt_scatter<<<(T + 255) / 256, 256, 0, stream>>>(x, cursor, rec, T);
        tt_embed_grouped<<<NPAIR, 256, 0, stream>>>(rec, counts, cursor,
                                                    c1, c2, c3, out);
    } else {
        const int blocks = (T + 3) / 4;
        tt_embed_kernel<<<blocks, 256, 0, stream>>>(x, c1, c2, c3, out, T);
    }
}

// Round 5
// 325.570 us; speedup vs baseline: 1.3770x; 1.0419x over previous
//
#include <hip/hip_runtime.h>

// TT-matrix embedding: vocab 50*60*60, embed 8*8*8, rank 16.
//
// FINAL (round-5 = revert to round-2, the empirical best at 324.2 us):
// counting-sort tokens by pair=(i1,i2), then ONE BLOCK PER PAIR-GROUP.
//   - Each wave computes its pair's t12 row (16 floats/lane across 64 lanes)
//     directly from c1/c2 in registers (identical FMA order since round 0 ->
//     identical absmax), then loops over the group's tokens (avg 43.7/pair)
//     doing the g3 contraction + store.
//   - Records are a single u32 (t<<6)|i3; pair is implied by blockIdx.
//
// Session post-mortem (why this is the floor):
//   - Timed region carries ~250 us of harness-fixed work: the 1 GiB workspace
//     poison (~163 us, top-5 every round) + output poison + memset litter.
//   - Our controllable portion is ~75 us with a hard floor of ~48 us
//     (268 MB out-write @ ~6.3 TB/s + ~1 MB sort traffic + 5 launches).
//   - Probes of the residual all failed: cooperative-kernel fusion of the sort
//     chain cost +124 us (grid.sync = global spin barrier + 1 block/CU cap);
//     fixed-capacity bucketing (3 launches, no hist/scan) measured +15 us vs
//     this chain; NT stores / scan variants within noise (+-8-10 us).
//   - R0 334 / R1 328 / R2 324 / R3 448 / R4 339: structural changes moving
//     ~580 MB of LLC traffic shifted totals by <2% -> remaining deltas are
//     below measurement noise. Write-roofline + fixed overhead reached.

#define M2M3  3600u
#define M3    60u
#define NPAIR 3000
#define NPAIR_PAD 3072

// ---------------- Phase 0: zero the histogram ----------------
__global__ __launch_bounds__(256) void tt_zero(unsigned* __restrict__ counts)
{
    const int i = blockIdx.x * blockDim.x + threadIdx.x;
    if (i < NPAIR_PAD) counts[i] = 0u;
}

// ---------------- Phase 1: histogram over pairs ----------------
__global__ __launch_bounds__(256) void tt_hist(
    const int* __restrict__ x, unsigned* __restrict__ counts, int T)
{
    const int t = blockIdx.x * blockDim.x + threadIdx.x;
    if (t >= T) return;
    const unsigned id = (unsigned)x[t];
    atomicAdd(&counts[id / M3], 1u);        // pair = id/60
}

// ---------------- Phase 2: exclusive scan (1 block) ----------------
__global__ __launch_bounds__(1024) void tt_scan(
    const unsigned* __restrict__ counts, unsigned* __restrict__ cursor)
{
    __shared__ unsigned buf[1024];
    const int tid = threadIdx.x;
    const int b = tid * 3;
    unsigned c0 = 0, c1 = 0, c2 = 0;
    if (b     < NPAIR) c0 = counts[b];
    if (b + 1 < NPAIR) c1 = counts[b + 1];
    if (b + 2 < NPAIR) c2 = counts[b + 2];
    const unsigned local = c0 + c1 + c2;
    buf[tid] = local;
    __syncthreads();
    for (int off = 1; off < 1024; off <<= 1) {
        const unsigned v = (tid >= off) ? buf[tid - off] : 0u;
        __syncthreads();
        buf[tid] += v;
        __syncthreads();
    }
    const unsigned excl = buf[tid] - local;
    if (b     < NPAIR) cursor[b]     = excl;
    if (b + 1 < NPAIR) cursor[b + 1] = excl + c0;
    if (b + 2 < NPAIR) cursor[b + 2] = excl + c0 + c1;
}

// ---------------- Phase 3: scatter records ----------------
__global__ __launch_bounds__(256) void tt_scatter(
    const int* __restrict__ x, unsigned* __restrict__ cursor,
    unsigned* __restrict__ rec, int T)
{
    const int t = blockIdx.x * blockDim.x + threadIdx.x;
    if (t >= T) return;
    const unsigned id   = (unsigned)x[t];
    const unsigned pair = id / M3;
    const unsigned i3   = id - pair * M3;
    const unsigned pos  = atomicAdd(&cursor[pair], 1u);
    rec[pos] = ((unsigned)t << 6) | i3;     // t:17b | i3:6b
}

// ---------------- Phase 4: per-pair-group embed ----------------
// grid = NPAIR blocks x 256 threads (4 waves). After scatter, cursor[p] = group END;
// start = cursor[p] - counts[p]. Each wave computes the pair's t12 row in registers
// (identical FMA order to all prior rounds), then serially processes its quarter
// of the group's tokens via readlane-broadcast records.
__global__ __launch_bounds__(256) void tt_embed_grouped(
    const unsigned* __restrict__ rec,
    const unsigned* __restrict__ counts,
    const unsigned* __restrict__ cursor,
    const float* __restrict__ c1,   // [50][8][16]
    const float* __restrict__ c2,   // [60][16][8][16]
    const float* __restrict__ c3,   // [60][16][8]
    float* __restrict__ out)        // [T][512]
{
    const int p    = blockIdx.x;            // pair = i1*60 + i2
    const int lane = threadIdx.x & 63;
    const int w    = threadIdx.x >> 6;      // wave 0..3
    const int a    = lane >> 3;
    const int b    = lane & 7;

    // group bounds -> scalar
    unsigned end = cursor[p];
    unsigned cnt = counts[p];
    end = __builtin_amdgcn_readfirstlane(end);
    cnt = __builtin_amdgcn_readfirstlane(cnt);
    const unsigned start = end - cnt;

    // this wave's contiguous share of the group
    const unsigned q = cnt >> 2, r = cnt & 3u;
    const unsigned nw = q + ((unsigned)w < r ? 1u : 0u);
    if (nw == 0) return;                    // no barriers below -> safe wave exit
    const unsigned bw = start + (unsigned)w * q + min((unsigned)w, r);

    // ---- compute t12 row for this pair, in registers ----
    // lane ab holds tf[s] = sum_r g1[a][r] * g2[r][b][s], s = 0..15
    const int i1 = p / 60;
    const int i2 = p - i1 * 60;
    const float4* __restrict__ g1v = (const float4*)(c1 + i1 * 128 + a * 16);
    const float*  __restrict__ g2  = c2 + i2 * 2048 + b * 16;

    float4 a1q[4];
#pragma unroll
    for (int k = 0; k < 4; ++k) a1q[k] = g1v[k];
    const float* a1f = (const float*)a1q;

    float4 t4[4];
#pragma unroll
    for (int k = 0; k < 4; ++k) t4[k] = make_float4(0.f, 0.f, 0.f, 0.f);
#pragma unroll
    for (int rr = 0; rr < 16; ++rr) {
        const float a1 = a1f[rr];
        const float4* row = (const float4*)(g2 + rr * 128);
#pragma unroll
        for (int k = 0; k < 4; ++k) {
            const float4 v = row[k];
            t4[k].x = fmaf(a1, v.x, t4[k].x);
            t4[k].y = fmaf(a1, v.y, t4[k].y);
            t4[k].z = fmaf(a1, v.z, t4[k].z);
            t4[k].w = fmaf(a1, v.w, t4[k].w);
        }
    }
    const float* tf = (const float*)t4;     // tf[s], s = 0..15

    // ---- token loop over this wave's share (batches of 64 records) ----
    for (unsigned off = 0; off < nw; off += 64u) {
        const unsigned m = min(64u, nw - off);      // wave-uniform
        unsigned rj = 0u;
        if ((unsigned)lane < m) rj = rec[bw + off + (unsigned)lane];

        for (unsigned j = 0; j < m; ++j) {
            const unsigned rv = __builtin_amdgcn_readlane(rj, (int)j);
            const unsigned t  = rv >> 6;
            const unsigned i3 = rv & 63u;

            const float4* __restrict__ g3 = (const float4*)(c3 + i3 * 128u);

            float o[8];
#pragma unroll
            for (int c = 0; c < 8; ++c) o[c] = 0.f;
#pragma unroll
            for (int s = 0; s < 16; ++s) {
                const float ts = tf[s];
                const float4 w0 = g3[s * 2 + 0];
                const float4 w1 = g3[s * 2 + 1];
                o[0] = fmaf(ts, w0.x, o[0]);
                o[1] = fmaf(ts, w0.y, o[1]);
                o[2] = fmaf(ts, w0.z, o[2]);
                o[3] = fmaf(ts, w0.w, o[3]);
                o[4] = fmaf(ts, w1.x, o[4]);
                o[5] = fmaf(ts, w1.y, o[5]);
                o[6] = fmaf(ts, w1.z, o[6]);
                o[7] = fmaf(ts, w1.w, o[7]);
            }

            float4* dst = (float4*)(out + (size_t)t * 512u + lane * 8);
            dst[0] = make_float4(o[0], o[1], o[2], o[3]);
            dst[1] = make_float4(o[4], o[5], o[6], o[7]);
        }
    }
}

// ---------------- Fallback A: two-phase via tab (needs 12.3 MB ws) ----------------
__global__ __launch_bounds__(256) void tt_pair_kernel(
    const float* __restrict__ c1, const float* __restrict__ c2,
    float* __restrict__ tab)
{
    const int pair = blockIdx.x;
    const int i1 = pair / 60;
    const int i2 = pair - i1 * 60;
    const int tid = threadIdx.x;
    const int qq = tid >> 6;
    const int ab = tid & 63;
    const int a  = ab >> 3;
    const int b  = ab & 7;
    const float* __restrict__ g1 = c1 + i1 * 128 + a * 16;
    const float* __restrict__ g2 = c2 + i2 * 2048 + b * 16 + qq * 4;
    float4 acc = make_float4(0.f, 0.f, 0.f, 0.f);
#pragma unroll
    for (int rr = 0; rr < 16; ++rr) {
        const float a1 = g1[rr];
        const float4 v = *(const float4*)(g2 + rr * 128);
        acc.x = fmaf(a1, v.x, acc.x);
        acc.y = fmaf(a1, v.y, acc.y);
        acc.z = fmaf(a1, v.z, acc.z);
        acc.w = fmaf(a1, v.w, acc.w);
    }
    *(float4*)(tab + (size_t)pair * 1024 + tid * 4) = acc;
}

__global__ __launch_bounds__(256) void tt_embed2_kernel(
    const int* __restrict__ x, const float* __restrict__ c3,
    const float* __restrict__ tab, float* __restrict__ out, int T)
{
    const int u    = (int)((blockIdx.x * blockDim.x + threadIdx.x) >> 6);
    const int lane = threadIdx.x & 63;
    if (u >= T) return;
    const unsigned id  = __builtin_amdgcn_readfirstlane((unsigned)x[u]);
    const unsigned i1  = id / M2M3;
    const unsigned rem = id - i1 * M2M3;
    const unsigned i2  = rem / M3;
    const unsigned i3  = rem - i2 * M3;
    const float* tp = tab + (size_t)(i1 * 60u + i2) * 1024u;
    float4 t[4];
#pragma unroll
    for (int k = 0; k < 4; ++k)
        t[k] = *(const float4*)(tp + k * 256 + lane * 4);
    const float* tf = (const float*)t;
    const float4* __restrict__ g3 = (const float4*)(c3 + i3 * 128u);
    float o[8];
#pragma unroll
    for (int c = 0; c < 8; ++c) o[c] = 0.f;
#pragma unroll
    for (int s = 0; s < 16; ++s) {
        const float ts = tf[s];
        const float4 w0 = g3[s * 2 + 0];
        const float4 w1 = g3[s * 2 + 1];
        o[0]=fmaf(ts,w0.x,o[0]); o[1]=fmaf(ts,w0.y,o[1]);
        o[2]=fmaf(ts,w0.z,o[2]); o[3]=fmaf(ts,w0.w,o[3]);
        o[4]=fmaf(ts,w1.x,o[4]); o[5]=fmaf(ts,w1.y,o[5]);
        o[6]=fmaf(ts,w1.z,o[6]); o[7]=fmaf(ts,w1.w,o[7]);
    }
    float4* dst = (float4*)(out + (size_t)u * 512 + lane * 8);
    dst[0] = make_float4(o[0], o[1], o[2], o[3]);
    dst[1] = make_float4(o[4], o[5], o[6], o[7]);
}

// ---------------- Fallback B: single-pass (tiny ws) ----------------
__global__ __launch_bounds__(256) void tt_embed_kernel(
    const int* __restrict__ x, const float* __restrict__ c1,
    const float* __restrict__ c2, const float* __restrict__ c3,
    float* __restrict__ out, int T)
{
    const int u    = (int)((blockIdx.x * blockDim.x + threadIdx.x) >> 6);
    const int lane = threadIdx.x & 63;
    if (u >= T) return;
    const int a = lane >> 3, b = lane & 7;
    const unsigned id  = (unsigned)x[u];
    const unsigned i1  = id / M2M3;
    const unsigned rem = id - i1 * M2M3;
    const unsigned i2  = rem / M3;
    const unsigned i3  = rem - i2 * M3;
    const float4* g1 = (const float4*)(c1 + i1 * 128u + a * 16);
    const float*  g2 = c2 + i2 * 2048u + b * 16;
    const float4* g3 = (const float4*)(c3 + i3 * 128u);
    float4 a1v[4];
#pragma unroll
    for (int k = 0; k < 4; ++k) a1v[k] = g1[k];
    const float* a1f = (const float*)a1v;
    float t12[16];
#pragma unroll
    for (int s = 0; s < 16; ++s) t12[s] = 0.f;
#pragma unroll
    for (int rr = 0; rr < 16; ++rr) {
        const float a1 = a1f[rr];
        const float4* row = (const float4*)(g2 + rr * 128);
#pragma unroll
        for (int k = 0; k < 4; ++k) {
            const float4 v = row[k];
            t12[k*4+0] = fmaf(a1, v.x, t12[k*4+0]);
            t12[k*4+1] = fmaf(a1, v.y, t12[k*4+1]);
            t12[k*4+2] = fmaf(a1, v.z, t12[k*4+2]);
            t12[k*4+3] = fmaf(a1, v.w, t12[k*4+3]);
        }
    }
    float o[8];
#pragma unroll
    for (int s = 0; s < 8; ++s) o[s] = 0.f;
#pragma unroll
    for (int s = 0; s < 16; ++s) {
        const float ts = t12[s];
        const float4 w0 = g3[s*2+0];
        const float4 w1 = g3[s*2+1];
        o[0]=fmaf(ts,w0.x,o[0]); o[1]=fmaf(ts,w0.y,o[1]);
        o[2]=fmaf(ts,w0.z,o[2]); o[3]=fmaf(ts,w0.w,o[3]);
        o[4]=fmaf(ts,w1.x,o[4]); o[5]=fmaf(ts,w1.y,o[5]);
        o[6]=fmaf(ts,w1.z,o[6]); o[7]=fmaf(ts,w1.w,o[7]);
    }
    float4* dst = (float4*)(out + (size_t)u * 512 + lane * 8);
    dst[0] = make_float4(o[0], o[1], o[2], o[3]);
    dst[1] = make_float4(o[4], o[5], o[6], o[7]);
}

extern "C" void kernel_launch(void* const* d_in, const int* in_sizes, int n_in,
                              void* d_out, int out_size, void* d_ws, size_t ws_size,
                              hipStream_t stream) {
    const int*   x  = (const int*)d_in[0];
    const float* c1 = (const float*)d_in[1];
    const float* c2 = (const float*)d_in[2];
    const float* c3 = (const float*)d_in[3];
    float* out = (float*)d_out;

    const int T = in_sizes[0];                        // 131072 tokens

    // sorted-path workspace: counts[3072] | cursor[3072] | rec[T]  (~550 KB)
    const size_t off_counts = 0;
    const size_t off_cursor = off_counts + (size_t)NPAIR_PAD * 4u;
    const size_t off_rec    = off_cursor + (size_t)NPAIR_PAD * 4u;
    const size_t need_sort  = off_rec + (size_t)T * 4u;
    const size_t tab_bytes  = (size_t)NPAIR * 1024u * sizeof(float);

    char* ws = (char*)d_ws;

    if (ws_size >= need_sort) {
        unsigned* counts = (unsigned*)(ws + off_counts);
        unsigned* cursor = (unsigned*)(ws + off_cursor);
        unsigned* rec    = (unsigned*)(ws + off_rec);

        tt_zero<<<(NPAIR_PAD + 255) / 256, 256, 0, stream>>>(counts);
        tt_hist<<<(T + 255) / 256, 256, 0, stream>>>(x, counts, T);
        tt_scan<<<1, 1024, 0, stream>>>(counts, cursor);
        tt_scatter<<<(T + 255) / 256, 256, 0, stream>>>(x, cursor, rec, T);
        tt_embed_grouped<<<NPAIR, 256, 0, stream>>>(rec, counts, cursor,
                                                    c1, c2, c3, out);
    } else if (ws_size >= tab_bytes) {
        float* tab = (float*)ws;
        tt_pair_kernel<<<NPAIR, 256, 0, stream>>>(c1, c2, tab);
        const int blocks = (T + 3) / 4;
        tt_embed2_kernel<<<blocks, 256, 0, stream>>>(x, c3, tab, out, T);
    } else {
        const int blocks = (T + 3) / 4;
        tt_embed_kernel<<<blocks, 256, 0, stream>>>(x, c1, c2, c3, out, T);
    }
}